// Round 1
// baseline (367.719 us; speedup 1.0000x reference)
//
#include <hip/hip_runtime.h>
#include <hip/hip_bf16.h>
#include <stdint.h>
#include <stddef.h>

// BiAttentionLayer: B=8, Tc=4096, Tq=1024, D=256, fp32 in/out.
// Math notes:
//  - s_c (w1 term) cancels in softmax/U/b -> never computed.
//  - exp() without running max is safe: |S| <= ~15 << 88 (fp32 exp range).
//  - b[i] = max_j softmax = exp(m)/l with m = max_j(s_cq+s_q), l = sum exp.

#define NB 8
#define TC 4096
#define TQ 1024
#define DD 256
#define JT 32
#define NJT (TQ / JT)   // 32 j-tiles

typedef __attribute__((ext_vector_type(16))) float  f32x16v;
typedef __attribute__((ext_vector_type(8)))  __bf16 bf16x8v;
typedef __attribute__((ext_vector_type(4)))  __bf16 bf16x4v;

// workspace layout (bytes); total ~8.6 MB
#define QB_OFF   0                            // bf16 [NB][TQ][DD]      (4 MiB)
#define QT_OFF   (QB_OFF + NB*TQ*DD*2)        // bf16 [NB][NJT][DD][JT] (4 MiB)
#define SQ_OFF   (QT_OFF + NB*TQ*DD*2)        // f32  [NB][TQ]
#define BV_OFF   (SQ_OFF + NB*TQ*4)           // f32  [NB][TC]
#define HV_OFF   (BV_OFF + NB*TC*4)           // f32  [NB][DD]

// ---------------- kernel 0: question preprocessing ----------------
// Per block: one (b, jtile) -> bf16 copy [j][d], transposed tile [d][j], s_q.
__global__ __launch_bounds__(256) void k_qprep(const float* __restrict__ question,
                                               const float* __restrict__ w,
                                               char* __restrict__ ws) {
  __bf16* qb = (__bf16*)(ws + QB_OFF);
  __bf16* qt = (__bf16*)(ws + QT_OFF);
  float*  sq = (float*)(ws + SQ_OFF);
  __shared__ __align__(16) __bf16 trans[DD][JT + 8];

  int bx = blockIdx.x;
  int b = bx >> 5, it = bx & 31;
  int j0 = it * JT;
  int t = threadIdx.x;
  int r = t >> 3;        // row (j) 0..31
  int seg = t & 7;       // d segment of 32

  const float* qrow = question + ((size_t)(b * TQ + j0 + r)) * DD + seg * 32;
  const float* w2 = w + DD;
  __bf16* qbrow = qb + ((size_t)(b * TQ + j0 + r)) * DD + seg * 32;

  float part = 0.f;
#pragma unroll
  for (int k = 0; k < 8; ++k) {
    float4 v  = *(const float4*)(qrow + 4 * k);
    float4 wv = *(const float4*)(w2 + seg * 32 + 4 * k);
    part += v.x * wv.x + v.y * wv.y + v.z * wv.z + v.w * wv.w;
    __bf16 b0 = (__bf16)v.x, b1 = (__bf16)v.y, b2 = (__bf16)v.z, b3 = (__bf16)v.w;
    int d = seg * 32 + 4 * k;
    trans[d + 0][r] = b0; trans[d + 1][r] = b1;
    trans[d + 2][r] = b2; trans[d + 3][r] = b3;
    bf16x4v pk = {b0, b1, b2, b3};
    *(bf16x4v*)(qbrow + 4 * k) = pk;
  }
  part += __shfl_xor(part, 1);
  part += __shfl_xor(part, 2);
  part += __shfl_xor(part, 4);
  if (seg == 0) sq[b * TQ + j0 + r] = part;
  __syncthreads();

  // write transposed tile: thread t owns d-row t (32 bf16 = 64 B contiguous)
  __bf16* dst = qt + ((size_t)((b * NJT + it) * DD + t)) * JT;
#pragma unroll
  for (int k = 0; k < 4; ++k) {
    bf16x8v v8;
#pragma unroll
    for (int e = 0; e < 8; ++e) v8[e] = trans[t][8 * k + e];
    *(bf16x8v*)(dst + 8 * k) = v8;
  }
}

// ---------------- kernel 1: fused scores+softmax+U + G chunks 0/1/2 ----------------
// Block = 128 threads (2 waves). Wave owns 32 i (columns). 512 blocks.
// mm1: S^T = q . cw3^T  (A = q from LDS [j][d], B = cw3 in regs) -> lane owns i = lane&31
// mm2: U^T = q^T . P^T  (A = q from LDS [d][j], B = P via LDS round-trip)
__global__ __launch_bounds__(128, 2) void k_main(const float* __restrict__ context,
                                                 const float* __restrict__ w,
                                                 const char* __restrict__ ws,
                                                 float* __restrict__ bv_out,
                                                 float* __restrict__ out) {
  const __bf16* qb = (const __bf16*)(ws + QB_OFF);
  const __bf16* qt = (const __bf16*)(ws + QT_OFF);
  const float*  sq = (const float*)(ws + SQ_OFF);

  // strides padded to multiples of 8 bf16 (16 B) to keep ds_read_b128 aligned;
  // 264*2=528B and 40*2=80B give even 32-bank spread for 32-row b128 reads.
  __shared__ __align__(16) __bf16 q_jd[JT][DD + 8];     // 16.5 KiB
  __shared__ __align__(16) __bf16 q_dj[DD][JT + 8];     // 20 KiB
  __shared__ __align__(16) __bf16 p_lds[2][32][JT + 8]; // 5 KiB
  __shared__ __align__(16) float  sq_lds[JT];

  int bx = blockIdx.x;
  int b = bx >> 6;
  int i0 = (bx & 63) * 64;
  int t = threadIdx.x;
  int wv = t >> 6;            // wave 0/1
  int n  = t & 31;            // col index within 32x32 tile
  int h  = (t >> 5) & 1;      // k-half of the lane
  int i  = i0 + wv * 32 + n;  // this lane's context row (i)

  // preload cw3 B-fragments: B[k=d][n=i] = context[i][d]*w3[d], 16 chunks of K=16
  bf16x8v cw3f[16];
  {
    const float* crow = context + ((size_t)(b * TC + i)) * DD;
    const float* w3 = w + 2 * DD;
#pragma unroll
    for (int c = 0; c < 16; ++c) {
      int d0 = c * 16 + h * 8;
      float4 f0 = *(const float4*)(crow + d0);
      float4 f1 = *(const float4*)(crow + d0 + 4);
      float4 g0 = *(const float4*)(w3 + d0);
      float4 g1 = *(const float4*)(w3 + d0 + 4);
      bf16x8v fr;
      fr[0] = (__bf16)(f0.x * g0.x); fr[1] = (__bf16)(f0.y * g0.y);
      fr[2] = (__bf16)(f0.z * g0.z); fr[3] = (__bf16)(f0.w * g0.w);
      fr[4] = (__bf16)(f1.x * g1.x); fr[5] = (__bf16)(f1.y * g1.y);
      fr[6] = (__bf16)(f1.z * g1.z); fr[7] = (__bf16)(f1.w * g1.w);
      cw3f[c] = fr;
    }
  }

  f32x16v zero16 = {0.f,0.f,0.f,0.f,0.f,0.f,0.f,0.f,0.f,0.f,0.f,0.f,0.f,0.f,0.f,0.f};
  f32x16v U[8];
#pragma unroll
  for (int mt = 0; mt < 8; ++mt) U[mt] = zero16;

  float m_run = -1e30f, l_run = 0.f;

  const uint4* qsrc   = (const uint4*)(qb + (size_t)b * TQ * DD);
  const uint4* qtsrc  = (const uint4*)(qt + (size_t)b * NJT * DD * JT);
  const float* sqb    = sq + b * TQ;

  for (int itq = 0; itq < NJT; ++itq) {
    // ---- stage q tiles (both layouts) + s_q into LDS ----
    {
      const uint4* s1 = qsrc + (size_t)itq * (JT * DD / 8);
#pragma unroll
      for (int k = 0; k < 8; ++k) {
        int c = t + 128 * k;
        *(uint4*)&q_jd[c >> 5][(c & 31) * 8] = s1[c];
      }
      const uint4* s2 = qtsrc + (size_t)itq * (DD * JT / 8);
#pragma unroll
      for (int k = 0; k < 8; ++k) {
        int c = t + 128 * k;
        *(uint4*)&q_dj[c >> 2][(c & 3) * 8] = s2[c];
      }
      if (t < 8) *(uint4*)&sq_lds[t * 4] = *(const uint4*)(sqb + itq * JT + t * 4);
    }
    __syncthreads();

    // ---- mm1: S^T tile (32j x 32i), K=256 ----
    f32x16v S = zero16;
#pragma unroll
    for (int c = 0; c < 16; ++c) {
      bf16x8v a = *(const bf16x8v*)&q_jd[n][c * 16 + h * 8];
      S = __builtin_amdgcn_mfma_f32_32x32x16_bf16(a, cw3f[c], S, 0, 0, 0);
    }

    // ---- P = exp(S + s_q); lazy max; row-sum; store bf16 P to per-wave LDS ----
#pragma unroll
    for (int rq = 0; rq < 4; ++rq) {
      float4 sq4 = *(const float4*)&sq_lds[8 * rq + 4 * h];
      float v0 = S[4 * rq + 0] + sq4.x;
      float v1 = S[4 * rq + 1] + sq4.y;
      float v2 = S[4 * rq + 2] + sq4.z;
      float v3 = S[4 * rq + 3] + sq4.w;
      m_run = fmaxf(m_run, fmaxf(fmaxf(v0, v1), fmaxf(v2, v3)));
      float e0 = __expf(v0), e1 = __expf(v1), e2 = __expf(v2), e3 = __expf(v3);
      l_run += (e0 + e1) + (e2 + e3);
      bf16x4v pk = {(__bf16)e0, (__bf16)e1, (__bf16)e2, (__bf16)e3};
      *(bf16x4v*)&p_lds[wv][n][8 * rq + 4 * h] = pk;
    }

    // ---- mm2: U^T += q^T . P^T  (8 d-mtiles, K=32 in 2 chunks) ----
    bf16x8v pf0 = *(const bf16x8v*)&p_lds[wv][n][h * 8];
    bf16x8v pf1 = *(const bf16x8v*)&p_lds[wv][n][16 + h * 8];
#pragma unroll
    for (int mt = 0; mt < 8; ++mt) {
      bf16x8v a0 = *(const bf16x8v*)&q_dj[mt * 32 + n][h * 8];
      U[mt] = __builtin_amdgcn_mfma_f32_32x32x16_bf16(a0, pf0, U[mt], 0, 0, 0);
    }
#pragma unroll
    for (int mt = 0; mt < 8; ++mt) {
      bf16x8v a1 = *(const bf16x8v*)&q_dj[mt * 32 + n][16 + h * 8];
      U[mt] = __builtin_amdgcn_mfma_f32_32x32x16_bf16(a1, pf1, U[mt], 0, 0, 0);
    }
    __syncthreads();
  }

  // ---- epilogue: finish l/m across the two k-halves; write G chunks 0,1,2 + b ----
  float lo = l_run + __shfl_xor(l_run, 32);
  float mo = fmaxf(m_run, __shfl_xor(m_run, 32));
  float rinv = 1.0f / lo;

  const float* crow = context + ((size_t)(b * TC + i)) * DD;
  float* orow = out + ((size_t)(b * TC + i)) * TQ;
#pragma unroll
  for (int mt = 0; mt < 8; ++mt) {
#pragma unroll
    for (int rq = 0; rq < 4; ++rq) {
      int d = mt * 32 + 8 * rq + 4 * h;
      float4 c4 = *(const float4*)(crow + d);
      float4 u4;
      u4.x = U[mt][4 * rq + 0] * rinv; u4.y = U[mt][4 * rq + 1] * rinv;
      u4.z = U[mt][4 * rq + 2] * rinv; u4.w = U[mt][4 * rq + 3] * rinv;
      *(float4*)(orow + d) = c4;
      *(float4*)(orow + DD + d) = u4;
      float4 cu; cu.x = c4.x * u4.x; cu.y = c4.y * u4.y;
      cu.z = c4.z * u4.z; cu.w = c4.w * u4.w;
      *(float4*)(orow + 2 * DD + d) = cu;
    }
  }
  if ((t & 63) < 32) bv_out[b * TC + i] = __expf(mo) * rinv;
}

// ---------------- kernel 2: h[b][d] = sum_i b[i] * context[b][i][d] ----------------
__global__ __launch_bounds__(256) void k_hred(const float* __restrict__ context,
                                              const char* __restrict__ ws,
                                              float* __restrict__ hv) {
  const float* bv = (const float*)(ws + BV_OFF);
  __shared__ float bsh[128];
  int bx = blockIdx.x;
  int b = bx >> 5, ch = bx & 31;
  int i0 = ch * 128;
  int t = threadIdx.x;
  if (t < 128) bsh[t] = bv[b * TC + i0 + t];
  __syncthreads();
  float acc = 0.f;
  const float* cp = context + ((size_t)(b * TC + i0)) * DD + t;
#pragma unroll 4
  for (int r = 0; r < 128; ++r) acc += bsh[r] * cp[(size_t)r * DD];
  atomicAdd(&hv[b * DD + t], acc);
}

// ---------------- kernel 3: G chunk 3 = context * H ----------------
__global__ __launch_bounds__(256) void k_final(const float* __restrict__ context,
                                               const char* __restrict__ ws,
                                               float* __restrict__ out) {
  const float* hv = (const float*)(ws + HV_OFF);
  int gid = blockIdx.x * 256 + threadIdx.x;   // over NB*TC*DD/4 float4s
  int row = gid >> 6;
  int d = (gid & 63) * 4;
  int b = row >> 12;
  float4 c4 = ((const float4*)context)[gid];
  float4 h4 = *(const float4*)(hv + b * DD + d);
  float4 r;
  r.x = c4.x * h4.x; r.y = c4.y * h4.y; r.z = c4.z * h4.z; r.w = c4.w * h4.w;
  *(float4*)(out + (size_t)row * TQ + 3 * DD + d) = r;
}

extern "C" void kernel_launch(void* const* d_in, const int* in_sizes, int n_in,
                              void* d_out, int out_size, void* d_ws, size_t ws_size,
                              hipStream_t stream) {
  (void)in_sizes; (void)n_in; (void)out_size; (void)ws_size;
  const float* context  = (const float*)d_in[0];
  const float* question = (const float*)d_in[1];
  const float* w        = (const float*)d_in[2];
  float* out = (float*)d_out;
  char* ws = (char*)d_ws;

  k_qprep<<<NB * NJT, 256, 0, stream>>>(question, w, ws);
  k_main<<<NB * (TC / 64), 128, 0, stream>>>(context, w, ws,
                                             (float*)(ws + BV_OFF), out);
  hipMemsetAsync(ws + HV_OFF, 0, NB * DD * sizeof(float), stream);
  k_hred<<<NB * 32, 256, 0, stream>>>(context, ws, (float*)(ws + HV_OFF));
  k_final<<<(NB * TC * DD / 4) / 256, 256, 0, stream>>>(context, ws, out);
}

// Round 2
// 278.125 us; speedup vs baseline: 1.3221x; 1.3221x over previous
//
#include <hip/hip_runtime.h>
#include <hip/hip_bf16.h>
#include <stdint.h>
#include <stddef.h>

// BiAttentionLayer: B=8, Tc=4096, Tq=1024, D=256, fp32 in/out.
// Math: s_c (w1) cancels in softmax/U/b. exp without running max is safe
// (|S+s_q| <= ~15). b[i] = exp(m)/l.
// Round-2: 16-i waves (16x16x32 MFMA) to cut accumulator regs 272->~175,
// 4-wave blocks share staged q-tile, mm2 B direct from L2 (swizzled layout).

#define NB 8
#define TC 4096
#define TQ 1024
#define DD 256
#define JT 32
#define NJT (TQ / JT)

typedef __attribute__((ext_vector_type(4)))  float  f32x4v;
typedef __attribute__((ext_vector_type(8)))  __bf16 bf16x8v;
typedef __attribute__((ext_vector_type(4)))  __bf16 bf16x4v;

// workspace layout (bytes)
#define QA_OFF   0                              // bf16 frag-order for mm1 A: [b][it][jm][c][L][8]  (4 MiB)
#define QX_OFF   (QA_OFF + NB*NJT*16*1024)      // bf16 frag-order for mm2 B: [b][it][mt][L][8]     (4 MiB)
#define SQ_OFF   (QX_OFF + NB*NJT*16*1024)      // f32 [NB][TQ]
#define BV_OFF   (SQ_OFF + NB*TQ*4)             // f32 [NB][TC]
#define HV_OFF   (BV_OFF + NB*TC*4)             // f32 [NB][DD]

// ---------------- kernel 0: question preprocessing ----------------
// One block per (b, jtile): stage q-tile bf16 in LDS, emit both fragment
// layouts + s_q.
__global__ __launch_bounds__(256) void k_qprep(const float* __restrict__ question,
                                               const float* __restrict__ w,
                                               char* __restrict__ ws) {
  uint4* qa = (uint4*)(ws + QA_OFF);
  uint4* qx = (uint4*)(ws + QX_OFF);
  float* sq = (float*)(ws + SQ_OFF);
  __shared__ __align__(16) __bf16 T[32][264];   // 528 B row stride (16-aligned)

  int bx = blockIdx.x;
  int b = bx >> 5, it = bx & 31;
  int t = threadIdx.x;
  int j = t >> 3;         // 0..31
  int seg = t & 7;        // d segment of 32

  const float* qrow = question + ((size_t)(b * TQ + it * JT + j)) * DD + seg * 32;
  const float* w2 = w + DD;

  float part = 0.f;
#pragma unroll
  for (int k = 0; k < 8; ++k) {
    float4 v  = *(const float4*)(qrow + 4 * k);
    float4 wv = *(const float4*)(w2 + seg * 32 + 4 * k);
    part += v.x * wv.x + v.y * wv.y + v.z * wv.z + v.w * wv.w;
    bf16x4v pk = {(__bf16)v.x, (__bf16)v.y, (__bf16)v.z, (__bf16)v.w};
    *(bf16x4v*)&T[j][seg * 32 + 4 * k] = pk;
  }
  part += __shfl_xor(part, 1);
  part += __shfl_xor(part, 2);
  part += __shfl_xor(part, 4);
  if (seg == 0) sq[b * TQ + it * JT + j] = part;
  __syncthreads();

  // qa chunks: ch = (jm*8+c)*64 + L ; element T[16*jm + (L&15)][32*c + 8*(L>>4) + o]
#pragma unroll
  for (int p = 0; p < 4; ++p) {
    int ch = t + 256 * p;
    int L = ch & 63, cc = ch >> 6;
    int jm = cc >> 3, c = cc & 7;
    int nh = L & 15, qh = L >> 4;
    uint4 v = *(const uint4*)&T[16 * jm + nh][32 * c + 8 * qh];
    qa[(size_t)(b * NJT + it) * 1024 + ch] = v;
  }
  // qx chunks: ch = mt*64 + L ; element T[8*(L>>4) + o][16*mt + (L&15)]
#pragma unroll
  for (int p = 0; p < 4; ++p) {
    int ch = t + 256 * p;
    int L = ch & 63, mt = ch >> 6;
    int nh = L & 15, qh = L >> 4;
    __bf16 e[8];
#pragma unroll
    for (int o = 0; o < 8; ++o) e[o] = T[8 * qh + o][16 * mt + nh];
    qx[(size_t)(b * NJT + it) * 1024 + ch] = *(const uint4*)e;
  }
}

// ---------------- kernel 1: fused scores+softmax+U + G chunks 0/1/2 ----------------
// 512 blocks x 256 thr (4 waves). Block owns 64 i; wave w owns 16 i.
// mm1: S^T[32j][16i] = q . cw3^T  (A = staged qa frags, B = cw3 regs)
// mm2: U[16i][256d] += P . q      (A = P via tiny per-wave LDS, B = qx from L2)
__global__ __launch_bounds__(256, 2) void k_main(const float* __restrict__ context,
                                                 const float* __restrict__ w,
                                                 const char* __restrict__ ws,
                                                 float* __restrict__ bv_out,
                                                 float* __restrict__ out) {
  const uint4*  qa = (const uint4*)(ws + QA_OFF);
  const __bf16* qx = (const __bf16*)(ws + QX_OFF);
  const float*  sq = (const float*)(ws + SQ_OFF);

  __shared__ __align__(16) __bf16 qa_lds[8192];     // 16 KiB staged qa tile
  __shared__ __align__(16) __bf16 pa_lds[4][16][40]; // per-wave P buffer (80 B rows)
  __shared__ __align__(16) float  sq_lds[32];

  int bx = blockIdx.x;
  int b = bx & 7;                 // XCD-affine batch mapping
  int ig = bx >> 3;               // 0..63
  int t = threadIdx.x;
  int wv = t >> 6;
  int lane = t & 63;
  int nh = lane & 15;             // col index (i for mm1 out, d for mm2 out)
  int qh = lane >> 4;             // quad
  int i0w = ig * 64 + wv * 16;    // wave's first i

  // cw3 B-frags: B[k=d][n=i] = context[i0w+nh][d]*w3[d], d = 32c + 8qh + o
  bf16x8v cw3f[8];
  {
    const float* crow = context + ((size_t)(b * TC + i0w + nh)) * DD;
    const float* w3 = w + 2 * DD;
#pragma unroll
    for (int c = 0; c < 8; ++c) {
      int d0 = 32 * c + 8 * qh;
      float4 f0 = *(const float4*)(crow + d0);
      float4 f1 = *(const float4*)(crow + d0 + 4);
      float4 g0 = *(const float4*)(w3 + d0);
      float4 g1 = *(const float4*)(w3 + d0 + 4);
      bf16x8v fr;
      fr[0] = (__bf16)(f0.x * g0.x); fr[1] = (__bf16)(f0.y * g0.y);
      fr[2] = (__bf16)(f0.z * g0.z); fr[3] = (__bf16)(f0.w * g0.w);
      fr[4] = (__bf16)(f1.x * g1.x); fr[5] = (__bf16)(f1.y * g1.y);
      fr[6] = (__bf16)(f1.z * g1.z); fr[7] = (__bf16)(f1.w * g1.w);
      cw3f[c] = fr;
    }
  }

  f32x4v U[16];
#pragma unroll
  for (int mt = 0; mt < 16; ++mt) U[mt] = (f32x4v){0.f, 0.f, 0.f, 0.f};
  float m_run = -1e30f, l_run = 0.f;

  const uint4* qa_b = qa + (size_t)b * NJT * 1024;
  const __bf16* qx_b = qx + (size_t)b * NJT * 8192;
  const float* sqb = sq + b * TQ;

  for (int itq = 0; itq < NJT; ++itq) {
    // stage qa tile (16 KiB) + s_q
    {
      const uint4* src = qa_b + (size_t)itq * 1024;
      uint4* dst = (uint4*)qa_lds;
#pragma unroll
      for (int p = 0; p < 4; ++p) {
        int idx = t + 256 * p;
        dst[idx] = src[idx];
      }
      if (t < 8) *(float4*)&sq_lds[t * 4] = *(const float4*)(sqb + itq * JT + t * 4);
    }
    __syncthreads();

    // mm1: S^T[32j][16i], K=256 in 8 chunks of 32
    f32x4v S0 = {0.f, 0.f, 0.f, 0.f}, S1 = {0.f, 0.f, 0.f, 0.f};
#pragma unroll
    for (int c = 0; c < 8; ++c) {
      bf16x8v a0 = *(const bf16x8v*)&qa_lds[((0 * 8 + c) * 64 + lane) * 8];
      bf16x8v a1 = *(const bf16x8v*)&qa_lds[((1 * 8 + c) * 64 + lane) * 8];
      S0 = __builtin_amdgcn_mfma_f32_16x16x32_bf16(a0, cw3f[c], S0, 0, 0, 0);
      S1 = __builtin_amdgcn_mfma_f32_16x16x32_bf16(a1, cw3f[c], S1, 0, 0, 0);
    }

    // P = exp(S + s_q): lane holds (i=nh, j = 16jm + 4qh + r)
    float4 sq0 = *(const float4*)&sq_lds[4 * qh];
    float4 sq1 = *(const float4*)&sq_lds[16 + 4 * qh];
    float e0 = __expf(S0[0] + sq0.x), e1 = __expf(S0[1] + sq0.y);
    float e2 = __expf(S0[2] + sq0.z), e3 = __expf(S0[3] + sq0.w);
    float f0 = __expf(S1[0] + sq1.x), f1 = __expf(S1[1] + sq1.y);
    float f2 = __expf(S1[2] + sq1.z), f3 = __expf(S1[3] + sq1.w);
    float v0 = fmaxf(fmaxf(S0[0] + sq0.x, S0[1] + sq0.y), fmaxf(S0[2] + sq0.z, S0[3] + sq0.w));
    float v1 = fmaxf(fmaxf(S1[0] + sq1.x, S1[1] + sq1.y), fmaxf(S1[2] + sq1.z, S1[3] + sq1.w));
    m_run = fmaxf(m_run, fmaxf(v0, v1));
    l_run += ((e0 + e1) + (e2 + e3)) + ((f0 + f1) + (f2 + f3));

    // write P to per-wave LDS in A-operand order: pa[i=nh][j]
    bf16x4v pk0 = {(__bf16)e0, (__bf16)e1, (__bf16)e2, (__bf16)e3};
    bf16x4v pk1 = {(__bf16)f0, (__bf16)f1, (__bf16)f2, (__bf16)f3};
    *(bf16x4v*)&pa_lds[wv][nh][4 * qh]      = pk0;
    *(bf16x4v*)&pa_lds[wv][nh][16 + 4 * qh] = pk1;

    // mm2 A-frag: A[m=i=nh][k=j=8qh+o] -> one b128 per lane
    bf16x8v af = *(const bf16x8v*)&pa_lds[wv][nh][8 * qh];

    // mm2: U[16i][16d] per mt, K=32 (full j-tile), B from L2 (coalesced)
    const __bf16* qxt = qx_b + (size_t)itq * 8192 + lane * 8;
#pragma unroll
    for (int mt = 0; mt < 16; ++mt) {
      bf16x8v bq = *(const bf16x8v*)(qxt + mt * 512);
      U[mt] = __builtin_amdgcn_mfma_f32_16x16x32_bf16(af, bq, U[mt], 0, 0, 0);
    }
    __syncthreads();
  }

  // reduce l, m across quads (lanes with same nh)
  float lo = l_run + __shfl_xor(l_run, 16);
  lo += __shfl_xor(lo, 32);
  float mo = fmaxf(m_run, __shfl_xor(m_run, 16));
  mo = fmaxf(mo, __shfl_xor(mo, 32));
  float rinv = 1.0f / lo;                 // valid for i = i0w + nh
  if ((t & 63) < 16) bv_out[b * TC + i0w + nh] = __expf(mo) * rinv;

  // epilogue: U rows are i = 4qh + r, cols d = 16mt + nh
  float rv[4];
#pragma unroll
  for (int r = 0; r < 4; ++r) rv[r] = __shfl(rinv, 4 * qh + r);

#pragma unroll
  for (int r = 0; r < 4; ++r) {
    int ig_row = i0w + 4 * qh + r;
    const float* crow = context + ((size_t)(b * TC + ig_row)) * DD;
    float* orow = out + ((size_t)(b * TC + ig_row)) * (4 * DD);
#pragma unroll
    for (int mt = 0; mt < 16; ++mt) {
      int d = 16 * mt + nh;
      float c = crow[d];
      float u = U[mt][r] * rv[r];
      orow[d] = c;
      orow[DD + d] = u;
      orow[2 * DD + d] = c * u;
    }
  }
}

// ---------------- kernel 2: h[b][d] = sum_i b[i] * context[b][i][d] ----------------
__global__ __launch_bounds__(256) void k_hred(const float* __restrict__ context,
                                              const char* __restrict__ ws,
                                              float* __restrict__ hv) {
  const float* bv = (const float*)(ws + BV_OFF);
  __shared__ float bsh[128];
  int bx = blockIdx.x;
  int b = bx >> 5, ch = bx & 31;
  int i0 = ch * 128;
  int t = threadIdx.x;
  if (t < 128) bsh[t] = bv[b * TC + i0 + t];
  __syncthreads();
  float acc = 0.f;
  const float* cp = context + ((size_t)(b * TC + i0)) * DD + t;
#pragma unroll 4
  for (int r = 0; r < 128; ++r) acc += bsh[r] * cp[(size_t)r * DD];
  atomicAdd(&hv[b * DD + t], acc);
}

// ---------------- kernel 3: G chunk 3 = context * H ----------------
__global__ __launch_bounds__(256) void k_final(const float* __restrict__ context,
                                               const char* __restrict__ ws,
                                               float* __restrict__ out) {
  const float* hv = (const float*)(ws + HV_OFF);
  int gid = blockIdx.x * 256 + threadIdx.x;
  int row = gid >> 6;
  int d = (gid & 63) * 4;
  int b = row >> 12;
  float4 c4 = ((const float4*)context)[gid];
  float4 h4 = *(const float4*)(hv + b * DD + d);
  float4 r;
  r.x = c4.x * h4.x; r.y = c4.y * h4.y; r.z = c4.z * h4.z; r.w = c4.w * h4.w;
  *(float4*)(out + (size_t)row * TQ + 3 * DD + d) = r;
}

extern "C" void kernel_launch(void* const* d_in, const int* in_sizes, int n_in,
                              void* d_out, int out_size, void* d_ws, size_t ws_size,
                              hipStream_t stream) {
  (void)in_sizes; (void)n_in; (void)out_size; (void)ws_size;
  const float* context  = (const float*)d_in[0];
  const float* question = (const float*)d_in[1];
  const float* w        = (const float*)d_in[2];
  float* out = (float*)d_out;
  char* ws = (char*)d_ws;

  k_qprep<<<NB * NJT, 256, 0, stream>>>(question, w, ws);
  k_main<<<NB * (TC / 64), 256, 0, stream>>>(context, w, ws,
                                             (float*)(ws + BV_OFF), out);
  hipMemsetAsync(ws + HV_OFF, 0, NB * DD * sizeof(float), stream);
  k_hred<<<NB * 32, 256, 0, stream>>>(context, ws, (float*)(ws + HV_OFF));
  k_final<<<(NB * TC * DD / 4) / 256, 256, 0, stream>>>(context, ws, out);
}